// Round 11
// baseline (485.728 us; speedup 1.0000x reference)
//
#include <hip/hip_runtime.h>
#include <cfloat>

// Problem constants
#define B_   4
#define C_   512
#define HW_  4096          // 64*64
#define R_   16384         // B_*HW_ rows of x
#define N_   16384         // memory bank rows
#define ALPHA_ 0.1f
#define SCALE_ ((float)(1000.0/49152.0))

typedef unsigned int u32;
typedef unsigned short u16;
typedef unsigned char u8;
typedef __attribute__((ext_vector_type(2))) unsigned long long u64x2;  // 16B = 2 fp8 frags
typedef __attribute__((ext_vector_type(4))) float f32x4;

typedef const __attribute__((address_space(1))) u32* gas_u32;
typedef __attribute__((address_space(3))) u32* las_u32;

__device__ __forceinline__ void async16(const void* g, void* l) {
    __builtin_amdgcn_global_load_lds((gas_u32)g, (las_u32)l, 16, 0, 0);
}

__device__ __forceinline__ u32 pk_fp8x4(float a, float b, float c, float d) {
    u32 v = __builtin_amdgcn_cvt_pk_fp8_f32(a, b, 0, false);   // bytes 0,1
    v = __builtin_amdgcn_cvt_pk_fp8_f32(c, d, v, true);        // bytes 2,3
    return v;
}

__device__ __forceinline__ void ins6(float (&t)[6], float v) {
    if (v < t[5]) {                     // rarely taken
        t[5] = v;
        #pragma unroll
        for (int q = 5; q >= 1; --q) {
            float lo = fminf(t[q-1], t[q]);
            float hi = fmaxf(t[q-1], t[q]);
            t[q-1] = lo; t[q] = hi;
        }
    }
}

// ---------- mem fp32 -> Mb in MFMA-FRAGMENT layout + m2 (exact fp32 norms) ----
//  Fragment layout (R20): Mb is 1-KB blocks, one per (n_tile = row/16,
//  K-half h = kb/64). Within a block, lane slot l = rq*16+fm (fm=row&15,
//  rq=(kb>>4)&3) holds bytes [l*16, l*16+16) = the EXACT canonical B-operand
//  (row fm, logical chunk rq) used since R7.  block offset =
//  (n_tile*8 + h)*1024;  byte = rq*256 + fm*16 + (kb&15).
__global__ void conv_mem_kernel(const float* __restrict__ mem,
                                u8* __restrict__ Mb, float* __restrict__ m2) {
    int w = threadIdx.x >> 6, l = threadIdx.x & 63;
    int row = blockIdx.x * 4 + w;
    const float4* p = (const float4*)(mem + (size_t)row * C_);
    float4 a = p[l], b = p[l + 64];
    float s = a.x*a.x + a.y*a.y + a.z*a.z + a.w*a.w
            + b.x*b.x + b.y*b.y + b.z*b.z + b.w*b.w;
    u8* base = Mb + (size_t)(row >> 4) * 8192;     // 8 fragments x 1KB per n_tile
    int fm = row & 15;
    int h1 = l >> 4, rqb = ((l >> 2) & 3) * 256 + (l & 3) * 4;
    *(u32*)(base + h1*1024       + fm*16 + rqb) = pk_fp8x4(a.x, a.y, a.z, a.w);
    *(u32*)(base + (4+h1)*1024   + fm*16 + rqb) = pk_fp8x4(b.x, b.y, b.z, b.w);
    #pragma unroll
    for (int off = 32; off > 0; off >>= 1) s += __shfl_down(s, off);
    if (l == 0) m2[row] = s;
}

// ---------- phi [b][c][n] -> Xb[g][c] fp8 (transpose via LDS) + fused x2 atomics ----------
__global__ void conv_phi_kernel(const float* __restrict__ phi, u8* __restrict__ Xb,
                                float* __restrict__ x2) {
    __shared__ float T[64][65];
    int t = threadIdx.x;
    int n0 = blockIdx.x * 64, c0 = blockIdx.y * 64, b = blockIdx.z;
    const float* src = phi + ((size_t)b * C_ + c0) * HW_ + n0;
    int l = t & 63, cg = t >> 6;
    float sq = 0.f;
    #pragma unroll
    for (int p = 0; p < 16; ++p) {
        int c = cg + p * 4;
        float v = src[(size_t)c * HW_ + l];      // coalesced along n
        T[c][l] = v;
        sq = fmaf(v, v, sq);
    }
    atomicAdd(&x2[(size_t)b * HW_ + n0 + l], sq);
    __syncthreads();
    int cq = t & 15, gl0 = t >> 4;
    #pragma unroll
    for (int p = 0; p < 4; ++p) {
        int gl = gl0 + p * 16;
        u32 v = pk_fp8x4(T[cq*4+0][gl], T[cq*4+1][gl],
                         T[cq*4+2][gl], T[cq*4+3][gl]);
        size_t g = (size_t)b * HW_ + n0 + gl;
        *(u32*)(Xb + g * C_ + c0 + cq*4) = v;
    }
}

// ---------- main GEMM+topk, R20 = R18 skeleton (273us: 16-row waves,
//  A-resident, XCD remap) with B SPLIT across pipes via FRAGMENT LAYOUT:
//  R18 pipe budget: LDS ds_read 768 cyc/block-stage (60%, BINDING), MFMA 620
//  (48%). This round halves the LDS pipe and puts the other half on the
//  (idle) vector-memory pipe — fixing R17's scatter failure by storing Mb in
//  fragment order (one B-operand load = ONE coalesced 1KB dwordx4, the same
//  addressing proven for A since R12):
//   * cols 0..3: LDS path — fragments staged LINEARLY (async16 wave-uniform
//     dst + lane*16; no swizzle needed), read back lane-linear ds_read_b128
//     (conflict-free by construction);
//   * cols 4..7: DIRECT loads from fragment blocks, issued at stage start,
//     consumed after the LDS half (latency hidden); the block's 4 waves read
//     the same fragments within one barrier interval -> L1/L2 hits (XCD remap
//     keeps the 2MB chunk L2-resident, R18-verified).
//  Operand bytes are byte-identical to R18's unswizzled reads -> same dot
//  products (invariance verified across R7-R19, absmax=0).
// ----------
template<int NC>
__global__ __launch_bounds__(256, 3) void gemm_topk_kernel(
    const u8* __restrict__ Xb, const u8* __restrict__ Mb,
    const float* __restrict__ m2, float* __restrict__ P /* [R][NC][6] */) {
    // [0,16384): 2 stage bufs (8KB: fragments f=0..7 at f*1024).
    // Merge phase reuses [0,24832) after the loop.
    __shared__ __align__(16) u8 smem[24832];
    const int t = threadIdx.x;
    const int w = t >> 6, l = t & 63;
    // ---- XCD-aware bijective remap (flat grid of 256*NC blocks, R18) ----
    const int id   = blockIdx.x;
    const int xcd  = id & 7;
    const int cy   = (xcd * NC) >> 3;            // chunk owned by this XCD
    const int xsub = xcd - cy * (8 / NC);        // 0..(8/NC)-1
    const int bx   = (id >> 3) + xsub * (256 * NC / 8);
    const int g0  = bx * 64;                     // block's 64 output rows
    const int n0c = cy * (N_ / NC);
    const int fm  = l & 15;
    const int rq  = l >> 4;

    // ---- A register-resident for the whole block (verified R15-R19) ----
    u64x2 ax[4][2];
    {
        const u8* Xr = Xb + (size_t)(g0 + w*16 + fm) * C_ + rq * 16;
        #pragma unroll
        for (int s = 0; s < 4; ++s) {
            ax[s][0] = *(const u64x2*)(Xr + s*128);
            ax[s][1] = *(const u64x2*)(Xr + s*128 + 64);
        }
    }

    float top[4][6];                     // row-slot = g0 + w*16 + rq*4 + j
    #pragma unroll
    for (int s4 = 0; s4 < 4; ++s4)
        #pragma unroll
        for (int q = 0; q < 6; ++q) top[s4][q] = FLT_MAX;

    const int n0t0 = n0c >> 4;           // fragment n_tile base of this chunk
    // prologue: stage (nt=0, s=0) cols 0..3 into buf0.
    // Wave w stages fragments f=w and f=4+w: f=(n*2+kh'), n=f>>1, kh'=f&1.
    {
        #pragma unroll
        for (int i = 0; i < 2; ++i)
            async16(Mb + ((size_t)(n0t0 + i*2 + (w>>1))*8 + (w&1))*1024 + l*16,
                    smem + i*4096 + w*1024);
    }
    __syncthreads();                     // buf0 ready

    const int NT = N_ / NC / 128;        // 32 at NC=4
    #pragma unroll 1
    for (int nt = 0; nt < NT; ++nt) {
        const int n0  = n0c + nt * 128;
        const int n0t = n0t0 + nt * 8;   // n_tile index of this 128-row panel

        f32x4 acc[8];
        #pragma unroll
        for (int n = 0; n < 8; ++n) acc[n] = (f32x4)0.f;

        #pragma unroll
        for (int s = 0; s < 4; ++s) {    // K=128 per stage; buf index = s&1
            // ---- (1) direct B loads for cols 4..7 (coalesced fragment loads,
            //      issued early; consumed after the LDS half) ----
            u64x2 bd[8];                 // [n'*2 + kh'], n'=0..3 -> col-group 4+n'
            #pragma unroll
            for (int np = 0; np < 4; ++np)
                #pragma unroll
                for (int kh = 0; kh < 2; ++kh)
                    bd[np*2+kh] = *(const u64x2*)(
                        Mb + ((size_t)(n0t + 4 + np)*8 + 2*s + kh)*1024 + l*16);
            // ---- (2) prefetch next stage cols 0..3 into buf^1 ----
            {
                const int nt2 = (s == 3) ? nt + 1 : nt;
                const int s2  = (s + 1) & 3;         // compile-time per unrolled s
                if (nt2 < NT) {
                    const int n0t2 = n0t0 + nt2 * 8;
                    u8* dst = smem + ((s+1)&1)*8192;
                    #pragma unroll
                    for (int i = 0; i < 2; ++i)
                        async16(Mb + ((size_t)(n0t2 + i*2 + (w>>1))*8
                                      + 2*s2 + (w&1))*1024 + l*16,
                                dst + i*4096 + w*1024);
                }
            }
            // ---- (3) LDS half: cols 0..3 (lane-linear, conflict-free) ----
            const u8* bufp = smem + (s&1)*8192;
            #pragma unroll
            for (int kh = 0; kh < 2; ++kh) {
                const u64x2 a = ax[s][kh];           // compile-time [s][kh]
                #pragma unroll
                for (int n = 0; n < 4; ++n) {
                    u64x2 bv = *(const u64x2*)(bufp + (n*2 + kh)*1024 + l*16);
                    // fragment bytes = canonical operand (row fm, chunk rq):
                    // same K-permutation on A and B -> same dot (verified R7).
                    acc[n] = __builtin_amdgcn_mfma_f32_16x16x32_fp8_fp8(
                        (long)a.x, (long)bv.x, acc[n], 0, 0, 0);
                    acc[n] = __builtin_amdgcn_mfma_f32_16x16x32_fp8_fp8(
                        (long)a.y, (long)bv.y, acc[n], 0, 0, 0);
                }
            }
            // ---- (4) direct half: cols 4..7 ----
            #pragma unroll
            for (int kh = 0; kh < 2; ++kh) {
                const u64x2 a = ax[s][kh];
                #pragma unroll
                for (int np = 0; np < 4; ++np) {
                    acc[4+np] = __builtin_amdgcn_mfma_f32_16x16x32_fp8_fp8(
                        (long)a.x, (long)bd[np*2+kh].x, acc[4+np], 0, 0, 0);
                    acc[4+np] = __builtin_amdgcn_mfma_f32_16x16x32_fp8_fp8(
                        (long)a.y, (long)bd[np*2+kh].y, acc[4+np], 0, 0, 0);
                }
            }

            if (s == 3) {
                // register epilogue: score = m2[c] - 2*dot (x2 added in finalize)
                float m2w[8];
                #pragma unroll
                for (int n = 0; n < 8; ++n) m2w[n] = m2[n0 + n * 16 + fm];
                #pragma unroll
                for (int j = 0; j < 4; ++j) {
                    float d0 = m2w[0] - 2.f * acc[0][j];
                    float d1 = m2w[1] - 2.f * acc[1][j];
                    float d2 = m2w[2] - 2.f * acc[2][j];
                    float d3 = m2w[3] - 2.f * acc[3][j];
                    float d4 = m2w[4] - 2.f * acc[4][j];
                    float d5 = m2w[5] - 2.f * acc[5][j];
                    float d6 = m2w[6] - 2.f * acc[6][j];
                    float d7 = m2w[7] - 2.f * acc[7][j];
                    float vmin = fminf(fminf(fminf(d0, d1), fminf(d2, d3)),
                                       fminf(fminf(d4, d5), fminf(d6, d7)));
                    float (&tt)[6] = top[j];
                    if (vmin < tt[5]) {      // slow path: rare after first tiles
                        ins6(tt, d0); ins6(tt, d1); ins6(tt, d2); ins6(tt, d3);
                        ins6(tt, d4); ins6(tt, d5); ins6(tt, d6); ins6(tt, d7);
                    }
                }
            }
            __syncthreads();   // next buf staged; buf s&1 free
        }
    }

    // final merge (single pass): per row, combine 16 fm-lanes' top-6 ->
    // per-chunk top-6 partial. 64 rows x stride 97 -> conflict-free reads.
    float* Mg = (float*)smem;            // 64*97 = 6208 floats = 24832 B
    #pragma unroll
    for (int j = 0; j < 4; ++j) {
        int lrow = w * 16 + rq * 4 + j;
        #pragma unroll
        for (int q = 0; q < 6; ++q)
            Mg[lrow * 97 + fm * 6 + q] = top[j][q];
    }
    __syncthreads();
    if (t < 64) {
        float t6[6];
        #pragma unroll
        for (int q = 0; q < 6; ++q) t6[q] = FLT_MAX;
        const float* row = Mg + t * 97;
        for (int v = 0; v < 96; ++v) ins6(t6, row[v]);
        float* dst = P + ((size_t)(g0 + t) * NC + cy) * 6;
        #pragma unroll
        for (int q = 0; q < 6; ++q) dst[q] = t6[q];
    }
}

// ---------- merge chunks + hinge loss ----------
template<int NC>
__global__ void finalize_kernel(const float* __restrict__ P, const float* __restrict__ x2,
                                const float* __restrict__ rp, float* __restrict__ out) {
    int g = blockIdx.x * 256 + threadIdx.x;
    float t6[6];
    #pragma unroll
    for (int q = 0; q < 6; ++q) t6[q] = FLT_MAX;
    const f32x4* pp = (const f32x4*)(P + (size_t)g * (NC * 6));
    #pragma unroll
    for (int q = 0; q < NC * 6 / 4; ++q) {
        f32x4 v = pp[q];
        ins6(t6, v.x); ins6(t6, v.y); ins6(t6, v.z); ins6(t6, v.w);
    }
    float x2g = x2[g];
    float rv = rp[0], r2 = rv * rv;
    float s = 0.f;
    #pragma unroll
    for (int i = 0; i < 3; ++i) {
        float d = fmaxf(t6[i] + x2g, 0.f);
        s += fmaxf(d - r2, 0.f);
    }
    #pragma unroll
    for (int i = 3; i < 6; ++i) {
        float d = fmaxf(t6[i] + x2g, 0.f);
        s += fmaxf(r2 - d - ALPHA_, 0.f);
    }
    #pragma unroll
    for (int off = 32; off > 0; off >>= 1) s += __shfl_down(s, off);
    __shared__ float red[4];
    int w = threadIdx.x >> 6, l = threadIdx.x & 63;
    if (l == 0) red[w] = s;
    __syncthreads();
    if (threadIdx.x == 0)
        atomicAdd(out, (red[0] + red[1] + red[2] + red[3]) * SCALE_);
}

// ================= Round-1 fp32 fallback (used only if ws too small) =================
#define TM 64
#define TN 64
#define KC 64
#define LDP 68

__global__ void m2_kernel(const float* __restrict__ mem, float* __restrict__ m2) {
    int wave = threadIdx.x >> 6, lane = threadIdx.x & 63;
    int row = blockIdx.x * 4 + wave;
    const float4* p = reinterpret_cast<const float4*>(mem + (size_t)row * C_);
    float4 a = p[lane], b = p[lane + 64];
    float s = a.x*a.x + a.y*a.y + a.z*a.z + a.w*a.w
            + b.x*b.x + b.y*b.y + b.z*b.z + b.w*b.w;
    #pragma unroll
    for (int off = 32; off > 0; off >>= 1) s += __shfl_down(s, off);
    if (lane == 0) m2[row] = s;
}

__global__ void x2f_kernel(const float* __restrict__ phi, float* __restrict__ x2) {
    int g = blockIdx.x * blockDim.x + threadIdx.x;
    int b = g >> 12;
    int n = g & 4095;
    const float* p = phi + (size_t)b * C_ * HW_ + n;
    float s = 0.f;
    #pragma unroll 8
    for (int c = 0; c < C_; ++c) {
        float v = p[(size_t)c * HW_];
        s = fmaf(v, v, s);
    }
    x2[g] = s;
}

__global__ __launch_bounds__(256) void dist_loss_kernel(
    const float* __restrict__ phi, const float* __restrict__ mem,
    const float* __restrict__ rp,  const float* __restrict__ m2,
    const float* __restrict__ x2,  float* __restrict__ out) {
    __shared__ float smem[2 * TM * LDP];
    float* xs = smem;
    float* ms = smem + TM * LDP;
    const int tid = threadIdx.x;
    const int tx = tid & 15, ty = tid >> 4;
    const int g0 = blockIdx.x * TM;
    const int b = g0 >> 12, n0img = g0 & 4095;
    const float* phiB = phi + (size_t)b * C_ * HW_ + n0img;
    float top[4][6];
    #pragma unroll
    for (int i = 0; i < 4; ++i)
        #pragma unroll
        for (int q = 0; q < 6; ++q) top[i][q] = FLT_MAX;
    float x2v[4];
    #pragma unroll
    for (int i = 0; i < 4; ++i) x2v[i] = x2[g0 + ty * 4 + i];
    for (int nt = 0; nt < N_ / TN; ++nt) {
        const int n0 = nt * TN;
        float acc[4][4];
        #pragma unroll
        for (int i = 0; i < 4; ++i)
            #pragma unroll
            for (int j = 0; j < 4; ++j) acc[i][j] = 0.f;
        for (int s = 0; s < C_ / KC; ++s) {
            const int k0 = s * KC;
            {
                int rr = tid & 63, cb = tid >> 6;
                #pragma unroll
                for (int p = 0; p < 16; ++p) {
                    int cc = p * 4 + cb;
                    xs[rr * LDP + cc] = phiB[(size_t)(k0 + cc) * HW_ + rr];
                }
            }
            {
                int kq = tid & 15, cb = tid >> 4;
                #pragma unroll
                for (int p = 0; p < 4; ++p) {
                    int c = p * 16 + cb;
                    float4 v = *reinterpret_cast<const float4*>(
                        mem + (size_t)(n0 + c) * C_ + k0 + kq * 4);
                    ms[(kq*4+0)*LDP + c] = v.x; ms[(kq*4+1)*LDP + c] = v.y;
                    ms[(kq*4+2)*LDP + c] = v.z; ms[(kq*4+3)*LDP + c] = v.w;
                }
            }
            __syncthreads();
            #pragma unroll
            for (int kq = 0; kq < KC / 4; ++kq) {
                float4 xa[4], mb[4];
                #pragma unroll
                for (int i = 0; i < 4; ++i)
                    xa[i] = *reinterpret_cast<const float4*>(&xs[(ty*4+i)*LDP + kq*4]);
                #pragma unroll
                for (int kk = 0; kk < 4; ++kk)
                    mb[kk] = *reinterpret_cast<const float4*>(&ms[(kq*4+kk)*LDP + tx*4]);
                #pragma unroll
                for (int i = 0; i < 4; ++i) {
                    const float xk[4] = {xa[i].x, xa[i].y, xa[i].z, xa[i].w};
                    #pragma unroll
                    for (int kk = 0; kk < 4; ++kk) {
                        const float mc[4] = {mb[kk].x, mb[kk].y, mb[kk].z, mb[kk].w};
                        #pragma unroll
                        for (int j = 0; j < 4; ++j)
                            acc[i][j] = fmaf(xk[kk], mc[j], acc[i][j]);
                    }
                }
            }
            __syncthreads();
        }
        #pragma unroll
        for (int j = 0; j < 4; ++j) {
            float m2v = m2[n0 + tx * 4 + j];
            #pragma unroll
            for (int i = 0; i < 4; ++i) {
                float d = fmaxf(x2v[i] + m2v - 2.f * acc[i][j], 0.f);
                ins6(top[i], d);
            }
        }
    }
    __syncthreads();
    float* mg = smem;
    #pragma unroll
    for (int i = 0; i < 4; ++i)
        #pragma unroll
        for (int q = 0; q < 6; ++q)
            mg[(ty*4+i)*97 + tx*6 + q] = top[i][q];
    __syncthreads();
    if (tid < 64) {
        float t6[6];
        #pragma unroll
        for (int q = 0; q < 6; ++q) t6[q] = FLT_MAX;
        const float* row = mg + tid * 97;
        for (int v = 0; v < 96; ++v) ins6(t6, row[v]);
        float rv = rp[0], r2 = rv * rv;
        float s = fmaxf(t6[0]-r2,0.f) + fmaxf(t6[1]-r2,0.f) + fmaxf(t6[2]-r2,0.f)
                + fmaxf(r2-t6[3]-ALPHA_,0.f) + fmaxf(r2-t6[4]-ALPHA_,0.f)
                + fmaxf(r2-t6[5]-ALPHA_,0.f);
        #pragma unroll
        for (int off = 32; off > 0; off >>= 1) s += __shfl_down(s, off);
        if (tid == 0) atomicAdd(out, s * SCALE_);
    }
}

extern "C" void kernel_launch(void* const* d_in, const int* in_sizes, int n_in,
                              void* d_out, int out_size, void* d_ws, size_t ws_size,
                              hipStream_t stream) {
    const float* phi = (const float*)d_in[0];
    const float* mem = (const float*)d_in[1];
    const float* rp  = (const float*)d_in[2];
    float* out = (float*)d_out;

    const size_t offX  = 0;
    const size_t offM  = (size_t)R_ * C_;                // Xb fp8: 8 MB
    const size_t offx2 = offM + (size_t)N_ * C_;         // Mb(frag) fp8: 8 MB
    const size_t offm2 = offx2 + (size_t)R_ * 4;
    const size_t offP  = offm2 + (size_t)N_ * 4;
    const size_t need4 = offP + (size_t)R_ * 4 * 6 * 4;  // ~17.8 MB (NC=4)

    hipMemsetAsync(out, 0, sizeof(float), stream);

    if (ws_size >= need4) {
        u8*    Xb = (u8*)((char*)d_ws + offX);
        u8*    Mb = (u8*)((char*)d_ws + offM);
        float* x2 = (float*)((char*)d_ws + offx2);
        float* m2 = (float*)((char*)d_ws + offm2);
        float* P  = (float*)((char*)d_ws + offP);

        hipMemsetAsync(x2, 0, (size_t)R_ * 4, stream);   // x2 accumulated atomically
        conv_mem_kernel<<<N_ / 4, 256, 0, stream>>>(mem, Mb, m2);
        conv_phi_kernel<<<dim3(HW_ / 64, C_ / 64, B_), 256, 0, stream>>>(phi, Xb, x2);
        gemm_topk_kernel<4><<<dim3(256 * 4, 1), 256, 0, stream>>>(Xb, Mb, m2, P);
        finalize_kernel<4><<<R_ / 256, 256, 0, stream>>>(P, x2, rp, out);
    } else {
        // fp32 fallback (verified round 1)
        float* m2 = (float*)d_ws;
        float* x2 = m2 + N_;
        m2_kernel<<<N_ / 4, 256, 0, stream>>>(mem, m2);
        x2f_kernel<<<R_ / 256, 256, 0, stream>>>(phi, x2);
        dist_loss_kernel<<<R_ / TM, 256, 0, stream>>>(phi, mem, rp, m2, x2, out);
    }
}

// Round 12
// 342.386 us; speedup vs baseline: 1.4187x; 1.4187x over previous
//
#include <hip/hip_runtime.h>
#include <cfloat>

// Problem constants
#define B_   4
#define C_   512
#define HW_  4096          // 64*64
#define R_   16384         // B_*HW_ rows of x
#define N_   16384         // memory bank rows
#define ALPHA_ 0.1f
#define SCALE_ ((float)(1000.0/49152.0))

typedef unsigned int u32;
typedef unsigned short u16;
typedef unsigned char u8;
typedef __attribute__((ext_vector_type(2))) unsigned long long u64x2;  // 16B = 2 fp8 frags
typedef __attribute__((ext_vector_type(4))) float f32x4;
typedef __attribute__((ext_vector_type(16))) float f32x16;             // 32x32 acc

typedef const __attribute__((address_space(1))) u32* gas_u32;
typedef __attribute__((address_space(3))) u32* las_u32;

__device__ __forceinline__ void async16(const void* g, void* l) {
    __builtin_amdgcn_global_load_lds((gas_u32)g, (las_u32)l, 16, 0, 0);
}

__device__ __forceinline__ u32 pk_fp8x4(float a, float b, float c, float d) {
    u32 v = __builtin_amdgcn_cvt_pk_fp8_f32(a, b, 0, false);   // bytes 0,1
    v = __builtin_amdgcn_cvt_pk_fp8_f32(c, d, v, true);        // bytes 2,3
    return v;
}

__device__ __forceinline__ void ins6(float (&t)[6], float v) {
    if (v < t[5]) {                     // rarely taken
        t[5] = v;
        #pragma unroll
        for (int q = 5; q >= 1; --q) {
            float lo = fminf(t[q-1], t[q]);
            float hi = fmaxf(t[q-1], t[q]);
            t[q-1] = lo; t[q] = hi;
        }
    }
}

// ---- 32x32x16 fragment addressing (R21) ----
// Fragment = one (row-tile r>>5, K-chunk-pair P) unit of 1 KB: lane slot l at
// l*16 holds [chunk 2P, slot l (8B) | chunk 2P+1, slot l (8B)], where
// slot l = (k-half l>>5)*32 + (row&31). This is exactly the per-lane operand
// of mfma_32x32x16_fp8 (own-dim = l&31, k-half = l>>5), so a lane-linear
// l*16 load (global or LDS) yields the operand pair directly.
// byte offset for (row, k-byte kb): (row>>5)*16384 + ((kb>>4)>>1)*1024
//   + ((((kb>>3)&1)<<5)+(row&31))*16 + ((kb>>4)&1)*8 + (kb&4)

// ---------- mem fp32 -> Mb fp8 fragment layout + m2 (exact fp32 norms) ----------
__global__ void conv_mem_kernel(const float* __restrict__ mem,
                                u8* __restrict__ Mb, float* __restrict__ m2) {
    int w = threadIdx.x >> 6, l = threadIdx.x & 63;
    int row = blockIdx.x * 4 + w;
    const float4* p = (const float4*)(mem + (size_t)row * C_);
    float4 a = p[l], b = p[l + 64];
    float s = a.x*a.x + a.y*a.y + a.z*a.z + a.w*a.w
            + b.x*b.x + b.y*b.y + b.z*b.z + b.w*b.w;
    u8* base = Mb + (size_t)(row >> 5) * 16384;
    int r31 = row & 31;
    {
        int kb = 4 * l;                     // k-bytes [4l, 4l+4)
        *(u32*)(base + ((kb>>4)>>1)*1024 + ((((kb>>3)&1)<<5) + r31)*16
                + ((kb>>4)&1)*8 + (kb&4)) = pk_fp8x4(a.x, a.y, a.z, a.w);
    }
    {
        int kb = 256 + 4 * l;               // k-bytes [256+4l, +4)
        *(u32*)(base + ((kb>>4)>>1)*1024 + ((((kb>>3)&1)<<5) + r31)*16
                + ((kb>>4)&1)*8 + (kb&4)) = pk_fp8x4(b.x, b.y, b.z, b.w);
    }
    #pragma unroll
    for (int off = 32; off > 0; off >>= 1) s += __shfl_down(s, off);
    if (l == 0) m2[row] = s;
}

// ---------- phi [b][c][n] -> Xb fragment layout + fused x2 atomics ----------
__global__ void conv_phi_kernel(const float* __restrict__ phi, u8* __restrict__ Xb,
                                float* __restrict__ x2) {
    __shared__ float T[64][65];
    int t = threadIdx.x;
    int n0 = blockIdx.x * 64, c0 = blockIdx.y * 64, b = blockIdx.z;
    const float* src = phi + ((size_t)b * C_ + c0) * HW_ + n0;
    int l = t & 63, cg = t >> 6;
    float sq = 0.f;
    #pragma unroll
    for (int p = 0; p < 16; ++p) {
        int c = cg + p * 4;
        float v = src[(size_t)c * HW_ + l];      // coalesced along n
        T[c][l] = v;
        sq = fmaf(v, v, sq);
    }
    atomicAdd(&x2[(size_t)b * HW_ + n0 + l], sq);
    __syncthreads();
    int cq = t & 15, gl0 = t >> 4;
    #pragma unroll
    for (int p = 0; p < 4; ++p) {
        int gl = gl0 + p * 16;
        u32 v = pk_fp8x4(T[cq*4+0][gl], T[cq*4+1][gl],
                         T[cq*4+2][gl], T[cq*4+3][gl]);
        int g = (int)((size_t)b * HW_ + n0 + gl);   // global X row
        int kb = c0 + cq * 4;
        *(u32*)(Xb + (size_t)(g >> 5) * 16384 + ((kb>>4)>>1)*1024
                + ((((kb>>3)&1)<<5) + (g & 31))*16 + ((kb>>4)&1)*8 + (kb&4)) = v;
    }
}

// ---------- main GEMM+topk, R21: 32x32x16 MFMA, swapped operands (D = M·X^T).
//  Rationale: ds_read-per-FLOP is set by M-rows-per-wave (B-reuse). 32 rows
//  with 16x16 blew registers (R0/R14) because per-row topk state scales with
//  rows. With 32x32 and D rows = BANK rows / D cols = X rows (C/D map
//  col=lane&31, verified in guide), each lane's 16 acc regs all belong to ONE
//  X row -> top[6] per lane (was 48 regs). Wave = 32 X rows x 128 bank rows:
//   * acc 4 x f32x16 = 64 AGPR; top 6; X streamed 8 regs/stage from
//     fragment-Xb (1KB coalesced loads, XCD-L2-resident per R18 remap);
//   * M staged to LDS in fragment layout: identity lane-linear async16 +
//     conflict-free l*16 ds_read (the mechanically-proven R20 LDS path);
//   * per block-stage (K=64): LDS 384 cyc (was 768), MFMA 516 (was 620).
//  Operand lane maps follow the verified 16x16 pattern (own-dim=l&31,
//  k-half=l>>5, identical on A and B so k-permutation cancels).
//  Skeleton: 2-buffer, 1 barrier/stage (R15-verified); XCD remap (R18).
// ----------
template<int NC>
__global__ __launch_bounds__(256, 3) void gemm_topk_kernel(
    const u8* __restrict__ Xb, const u8* __restrict__ Mb,
    const float* __restrict__ m2, float* __restrict__ P /* [R][NC][6] */) {
    // [0,16384): 2 stage bufs (8KB = 4 tiles x 2 pairs x 1KB).
    // Merge phase reuses [0, 128*13*4=6656).
    __shared__ __align__(16) u8 smem[16384];
    const int t = threadIdx.x;
    const int w = t >> 6, l = t & 63;
    // ---- XCD-aware bijective remap (flat grid of 128*NC blocks) ----
    const int id   = blockIdx.x;
    const int xcd  = id & 7;
    const int cy   = (xcd * NC) >> 3;            // chunk owned by this XCD
    const int xsub = xcd - cy * (8 / NC);        // 0..(8/NC)-1
    const int bx   = (id >> 3) + xsub * (128 * NC / 8);
    const int g0   = bx * 128;                   // block's 128 X rows
    const int n0c  = cy * (N_ / NC);
    const int n32c = n0c >> 5;                   // bank fragment-tile base
    const int xt   = (g0 >> 5) + w;              // wave's X fragment tile
    const int col  = l & 31, h = l >> 5;

    float top[6];
    #pragma unroll
    for (int q = 0; q < 6; ++q) top[q] = FLT_MAX;

    // prologue: stage gs=0 (nt=0, s=0) into buf0; wave w stages bank-tile w.
    {
        const u8* Msrc = Mb + (size_t)(n32c + w) * 16384;
        #pragma unroll
        for (int pp = 0; pp < 2; ++pp)
            async16(Msrc + pp*1024 + l*16, smem + w*2048 + pp*1024);
    }
    __syncthreads();                     // buf0 ready

    const int NT = N_ / NC / 128;        // 16 at NC=8
    #pragma unroll 1
    for (int nt = 0; nt < NT; ++nt) {
        f32x16 acc[4];
        #pragma unroll
        for (int n = 0; n < 4; ++n) acc[n] = (f32x16)0.f;

        #pragma unroll
        for (int s = 0; s < 8; ++s) {    // K=64 per stage (2 chunk-pairs)
            const int cur = (nt * 8 + s) & 1;
            // ---- X stream for this stage (coalesced 1KB fragment loads) ----
            u64x2 xv0 = *(const u64x2*)(Xb + ((size_t)xt*16 + 2*s  )*1024 + l*16);
            u64x2 xv1 = *(const u64x2*)(Xb + ((size_t)xt*16 + 2*s+1)*1024 + l*16);
            // ---- prefetch next stage into buf^1 ----
            {
                const int gs2 = nt * 8 + s + 1;
                if (gs2 < NT * 8) {
                    const int nt2 = gs2 >> 3, s2 = gs2 & 7;
                    const u8* Msrc = Mb + (size_t)(n32c + nt2*4 + w) * 16384
                                        + (size_t)(2*s2) * 1024;
                    u8* dst = smem + (cur^1)*8192 + w*2048;
                    #pragma unroll
                    for (int pp = 0; pp < 2; ++pp)
                        async16(Msrc + pp*1024 + l*16, dst + pp*1024);
                }
            }
            // ---- compute from buf cur: 8 ds_read_b128 + 16 MFMA ----
            const u8* buf = smem + cur*8192;
            #pragma unroll
            for (int pp = 0; pp < 2; ++pp) {
                const u64x2 xv = pp ? xv1 : xv0;
                #pragma unroll
                for (int tt = 0; tt < 4; ++tt) {
                    u64x2 bm = *(const u64x2*)(buf + tt*2048 + pp*1024 + l*16);
                    // A = M (D rows = bank rows), B = X (D cols = X rows).
                    // Same chunk on both sides; k-permutation cancels.
                    acc[tt] = __builtin_amdgcn_mfma_f32_32x32x16_fp8_fp8(
                        (long)bm.x, (long)xv.x, acc[tt], 0, 0, 0);
                    acc[tt] = __builtin_amdgcn_mfma_f32_32x32x16_fp8_fp8(
                        (long)bm.y, (long)xv.y, acc[tt], 0, 0, 0);
                }
            }

            if (s == 7) {
                // epilogue: score = m2[bank] - 2*dot (x2 added in finalize).
                // D row map (verified): bank = (reg&3) + 8*(reg>>2) + 4*h.
                // reg = gqd*4 + c  ->  bank = c + 8*gqd + 4*h.
                const int n0 = n0c + nt * 128;
                #pragma unroll
                for (int tt = 0; tt < 4; ++tt) {
                    const f32x4* m2p = (const f32x4*)(m2 + n0 + tt*32 + h*4);
                    float dv[16];
                    float vmin = FLT_MAX;
                    #pragma unroll
                    for (int gq = 0; gq < 4; ++gq) {
                        f32x4 mv = m2p[gq * 2];          // m2[.. + 8*gq .. +4)
                        #pragma unroll
                        for (int c = 0; c < 4; ++c) {
                            float d = mv[c] - 2.f * acc[tt][gq*4 + c];
                            dv[gq*4 + c] = d;
                            vmin = fminf(vmin, d);
                        }
                    }
                    if (vmin < top[5]) {                 // rare after first tiles
                        #pragma unroll
                        for (int i = 0; i < 16; ++i) ins6(top, dv[i]);
                    }
                }
            }
            __syncthreads();   // next buf staged; buf cur free
        }
    }

    // final merge: x-row r is held by 2 lanes (h=0,1) covering disjoint bank
    // rows -> merge 2x top-6 per row. Stride 13 -> conflict-free.
    float* Mg = (float*)smem;            // 128*13 floats = 6656 B
    {
        int lrow = w * 32 + col;
        #pragma unroll
        for (int q = 0; q < 6; ++q)
            Mg[lrow * 13 + h * 6 + q] = top[q];
    }
    __syncthreads();
    if (t < 128) {
        float t6[6];
        #pragma unroll
        for (int q = 0; q < 6; ++q) t6[q] = FLT_MAX;
        const float* row = Mg + t * 13;
        #pragma unroll
        for (int v = 0; v < 12; ++v) ins6(t6, row[v]);
        float* dst = P + ((size_t)(g0 + t) * NC + cy) * 6;
        #pragma unroll
        for (int q = 0; q < 6; ++q) dst[q] = t6[q];
    }
}

// ---------- merge chunks + hinge loss ----------
template<int NC>
__global__ void finalize_kernel(const float* __restrict__ P, const float* __restrict__ x2,
                                const float* __restrict__ rp, float* __restrict__ out) {
    int g = blockIdx.x * 256 + threadIdx.x;
    float t6[6];
    #pragma unroll
    for (int q = 0; q < 6; ++q) t6[q] = FLT_MAX;
    const f32x4* pp = (const f32x4*)(P + (size_t)g * (NC * 6));
    #pragma unroll
    for (int q = 0; q < NC * 6 / 4; ++q) {
        f32x4 v = pp[q];
        ins6(t6, v.x); ins6(t6, v.y); ins6(t6, v.z); ins6(t6, v.w);
    }
    float x2g = x2[g];
    float rv = rp[0], r2 = rv * rv;
    float s = 0.f;
    #pragma unroll
    for (int i = 0; i < 3; ++i) {
        float d = fmaxf(t6[i] + x2g, 0.f);
        s += fmaxf(d - r2, 0.f);
    }
    #pragma unroll
    for (int i = 3; i < 6; ++i) {
        float d = fmaxf(t6[i] + x2g, 0.f);
        s += fmaxf(r2 - d - ALPHA_, 0.f);
    }
    #pragma unroll
    for (int off = 32; off > 0; off >>= 1) s += __shfl_down(s, off);
    __shared__ float red[4];
    int w = threadIdx.x >> 6, l = threadIdx.x & 63;
    if (l == 0) red[w] = s;
    __syncthreads();
    if (threadIdx.x == 0)
        atomicAdd(out, (red[0] + red[1] + red[2] + red[3]) * SCALE_);
}

// ================= Round-1 fp32 fallback (used only if ws too small) =================
#define TM 64
#define TN 64
#define KC 64
#define LDP 68

__global__ void m2_kernel(const float* __restrict__ mem, float* __restrict__ m2) {
    int wave = threadIdx.x >> 6, lane = threadIdx.x & 63;
    int row = blockIdx.x * 4 + wave;
    const float4* p = reinterpret_cast<const float4*>(mem + (size_t)row * C_);
    float4 a = p[lane], b = p[lane + 64];
    float s = a.x*a.x + a.y*a.y + a.z*a.z + a.w*a.w
            + b.x*b.x + b.y*b.y + b.z*b.z + b.w*b.w;
    #pragma unroll
    for (int off = 32; off > 0; off >>= 1) s += __shfl_down(s, off);
    if (lane == 0) m2[row] = s;
}

__global__ void x2f_kernel(const float* __restrict__ phi, float* __restrict__ x2) {
    int g = blockIdx.x * blockDim.x + threadIdx.x;
    int b = g >> 12;
    int n = g & 4095;
    const float* p = phi + (size_t)b * C_ * HW_ + n;
    float s = 0.f;
    #pragma unroll 8
    for (int c = 0; c < C_; ++c) {
        float v = p[(size_t)c * HW_];
        s = fmaf(v, v, s);
    }
    x2[g] = s;
}

__global__ __launch_bounds__(256) void dist_loss_kernel(
    const float* __restrict__ phi, const float* __restrict__ mem,
    const float* __restrict__ rp,  const float* __restrict__ m2,
    const float* __restrict__ x2,  float* __restrict__ out) {
    __shared__ float smem[2 * TM * LDP];
    float* xs = smem;
    float* ms = smem + TM * LDP;
    const int tid = threadIdx.x;
    const int tx = tid & 15, ty = tid >> 4;
    const int g0 = blockIdx.x * TM;
    const int b = g0 >> 12, n0img = g0 & 4095;
    const float* phiB = phi + (size_t)b * C_ * HW_ + n0img;
    float top[4][6];
    #pragma unroll
    for (int i = 0; i < 4; ++i)
        #pragma unroll
        for (int q = 0; q < 6; ++q) top[i][q] = FLT_MAX;
    float x2v[4];
    #pragma unroll
    for (int i = 0; i < 4; ++i) x2v[i] = x2[g0 + ty * 4 + i];
    for (int nt = 0; nt < N_ / TN; ++nt) {
        const int n0 = nt * TN;
        float acc[4][4];
        #pragma unroll
        for (int i = 0; i < 4; ++i)
            #pragma unroll
            for (int j = 0; j < 4; ++j) acc[i][j] = 0.f;
        for (int s = 0; s < C_ / KC; ++s) {
            const int k0 = s * KC;
            {
                int rr = tid & 63, cb = tid >> 6;
                #pragma unroll
                for (int p = 0; p < 16; ++p) {
                    int cc = p * 4 + cb;
                    xs[rr * LDP + cc] = phiB[(size_t)(k0 + cc) * HW_ + rr];
                }
            }
            {
                int kq = tid & 15, cb = tid >> 4;
                #pragma unroll
                for (int p = 0; p < 4; ++p) {
                    int c = p * 16 + cb;
                    float4 v = *reinterpret_cast<const float4*>(
                        mem + (size_t)(n0 + c) * C_ + k0 + kq * 4);
                    ms[(kq*4+0)*LDP + c] = v.x; ms[(kq*4+1)*LDP + c] = v.y;
                    ms[(kq*4+2)*LDP + c] = v.z; ms[(kq*4+3)*LDP + c] = v.w;
                }
            }
            __syncthreads();
            #pragma unroll
            for (int kq = 0; kq < KC / 4; ++kq) {
                float4 xa[4], mb[4];
                #pragma unroll
                for (int i = 0; i < 4; ++i)
                    xa[i] = *reinterpret_cast<const float4*>(&xs[(ty*4+i)*LDP + kq*4]);
                #pragma unroll
                for (int kk = 0; kk < 4; ++kk)
                    mb[kk] = *reinterpret_cast<const float4*>(&ms[(kq*4+kk)*LDP + tx*4]);
                #pragma unroll
                for (int i = 0; i < 4; ++i) {
                    const float xk[4] = {xa[i].x, xa[i].y, xa[i].z, xa[i].w};
                    #pragma unroll
                    for (int kk = 0; kk < 4; ++kk) {
                        const float mc[4] = {mb[kk].x, mb[kk].y, mb[kk].z, mb[kk].w};
                        #pragma unroll
                        for (int j = 0; j < 4; ++j)
                            acc[i][j] = fmaf(xk[kk], mc[j], acc[i][j]);
                    }
                }
            }
            __syncthreads();
        }
        #pragma unroll
        for (int j = 0; j < 4; ++j) {
            float m2v = m2[n0 + tx * 4 + j];
            #pragma unroll
            for (int i = 0; i < 4; ++i) {
                float d = fmaxf(x2v[i] + m2v - 2.f * acc[i][j], 0.f);
                ins6(top[i], d);
            }
        }
    }
    __syncthreads();
    float* mg = smem;
    #pragma unroll
    for (int i = 0; i < 4; ++i)
        #pragma unroll
        for (int q = 0; q < 6; ++q)
            mg[(ty*4+i)*97 + tx*6 + q] = top[i][q];
    __syncthreads();
    if (tid < 64) {
        float t6[6];
        #pragma unroll
        for (int q = 0; q < 6; ++q) t6[q] = FLT_MAX;
        const float* row = mg + tid * 97;
        for (int v = 0; v < 96; ++v) ins6(t6, row[v]);
        float rv = rp[0], r2 = rv * rv;
        float s = fmaxf(t6[0]-r2,0.f) + fmaxf(t6[1]-r2,0.f) + fmaxf(t6[2]-r2,0.f)
                + fmaxf(r2-t6[3]-ALPHA_,0.f) + fmaxf(r2-t6[4]-ALPHA_,0.f)
                + fmaxf(r2-t6[5]-ALPHA_,0.f);
        #pragma unroll
        for (int off = 32; off > 0; off >>= 1) s += __shfl_down(s, off);
        if (tid == 0) atomicAdd(out, s * SCALE_);
    }
}

extern "C" void kernel_launch(void* const* d_in, const int* in_sizes, int n_in,
                              void* d_out, int out_size, void* d_ws, size_t ws_size,
                              hipStream_t stream) {
    const float* phi = (const float*)d_in[0];
    const float* mem = (const float*)d_in[1];
    const float* rp  = (const float*)d_in[2];
    float* out = (float*)d_out;

    const size_t offX  = 0;
    const size_t offM  = (size_t)R_ * C_;                // Xb fp8 frags: 8 MB
    const size_t offx2 = offM + (size_t)N_ * C_;         // Mb fp8 frags: 8 MB
    const size_t offm2 = offx2 + (size_t)R_ * 4;
    const size_t offP  = offm2 + (size_t)N_ * 4;
    const size_t need8 = offP + (size_t)R_ * 8 * 6 * 4;  // ~19.9 MB (NC=8)
    const size_t need4 = offP + (size_t)R_ * 4 * 6 * 4;  // ~17.8 MB (NC=4)

    hipMemsetAsync(out, 0, sizeof(float), stream);

    if (ws_size >= need4) {
        u8*    Xb = (u8*)((char*)d_ws + offX);
        u8*    Mb = (u8*)((char*)d_ws + offM);
        float* x2 = (float*)((char*)d_ws + offx2);
        float* m2 = (float*)((char*)d_ws + offm2);
        float* P  = (float*)((char*)d_ws + offP);

        hipMemsetAsync(x2, 0, (size_t)R_ * 4, stream);   // x2 accumulated atomically
        conv_mem_kernel<<<N_ / 4, 256, 0, stream>>>(mem, Mb, m2);
        conv_phi_kernel<<<dim3(HW_ / 64, C_ / 64, B_), 256, 0, stream>>>(phi, Xb, x2);
        if (ws_size >= need8) {
            gemm_topk_kernel<8><<<dim3(128 * 8, 1), 256, 0, stream>>>(Xb, Mb, m2, P);
            finalize_kernel<8><<<R_ / 256, 256, 0, stream>>>(P, x2, rp, out);
        } else {
            gemm_topk_kernel<4><<<dim3(128 * 4, 1), 256, 0, stream>>>(Xb, Mb, m2, P);
            finalize_kernel<4><<<R_ / 256, 256, 0, stream>>>(P, x2, rp, out);
        }
    } else {
        // fp32 fallback (verified round 1)
        float* m2 = (float*)d_ws;
        float* x2 = m2 + N_;
        m2_kernel<<<N_ / 4, 256, 0, stream>>>(mem, m2);
        x2f_kernel<<<R_ / 256, 256, 0, stream>>>(phi, x2);
        dist_loss_kernel<<<R_ / TM, 256, 0, stream>>>(phi, mem, rp, m2, x2, out);
    }
}